// Round 3
// baseline (216.607 us; speedup 1.0000x reference)
//
#include <hip/hip_runtime.h>
#include <math.h>

// YOLO loss: pred/target (BATCH,7,7,30) f32, choice (BATCH,7,7) i32
// -> 4 scalars (loc, cls, obj, noobj).
// Round-12: phase-free direct streaming. Evidence: r11 (gl_lds + counted
// vmcnt, 2 blk/CU) = 80us @1.2TB/s -> barrier-phased lockstep starves the
// memory pipe; harness fill kernels prove 6.8 TB/s at 9% occupancy with
// ZERO barriers. So: drop LDS + barriers entirely. Each thread loads its
// own cell's 30 floats as 15x float2 (cell stride 120B -> always 8B
// aligned); a wave's 15 loads cover 60 cache lines with 100% utilization;
// NORMAL loads (no nt) so L1 absorbs intra-wave line re-touches.
// T=128, GRID=1280, cell = tid + 128*(b + k*1280): identical cell->lane->
// accumulator mapping as round-7 baseline (its waves 2-3 never computed),
// reduction rows 2,3 written as 0.0 -> outputs bitwise identical.

constexpr int NCH = 30;    // 5*B + C
constexpr int CC  = 20;    // classes
constexpr int ROW = 8;     // floats per block's partial row (32 B)
constexpr int T   = 128;   // threads per block (2 waves) = cells per chunk
constexpr int CPB = 128;   // cells per chunk (== T)
constexpr int GRID = 1280; // same chunk->block mapping as baseline

__global__ __launch_bounds__(T) void yolo_main(
    const float* __restrict__ pred, const float* __restrict__ target,
    const int* __restrict__ choice, float* __restrict__ ws,
    int ncells, int nchunks)
{
    const int tid = threadIdx.x;

    float a_loc = 0.f, a_ce = 0.f, a_obj = 0.f, a_no = 0.f;
    float a_nob = 0.f, a_nno = 0.f;

    for (long long c = blockIdx.x; c < nchunks; c += GRID) {
        long long cell = c * CPB + tid;
        if (cell < (long long)ncells) {
            const float* sp  = pred   + cell * NCH;
            const float* stt = target + cell * NCH;
            float p[NCH], t[NCH];
            #pragma unroll
            for (int i = 0; i < NCH / 2; ++i) {
                float2 v = *(const float2*)&sp[2 * i];  p[2*i] = v.x; p[2*i+1] = v.y;
            }
            #pragma unroll
            for (int i = 0; i < NCH / 2; ++i) {
                float2 w = *(const float2*)&stt[2 * i]; t[2*i] = w.x; t[2*i+1] = w.y;
            }
            int myc = choice[cell];
            bool csel = myc != 0;

            float tconf = t[4];
            bool  obj = tconf > 0.0f;
            float m = obj ? 1.0f : 0.0f;

            float pxy0 = csel ? p[0] : p[5];
            float pxy1 = csel ? p[1] : p[6];
            float pwh0 = csel ? p[2] : p[7];
            float pwh1 = csel ? p[3] : p[8];
            float pobj = csel ? p[4] : p[9];
            float txy0 = csel ? t[0] : t[5];
            float txy1 = csel ? t[1] : t[6];
            float twh0 = csel ? t[2] : t[7];
            float twh1 = csel ? t[3] : t[8];
            if (!obj) { twh0 = 1.0f; twh1 = 1.0f; }
            float tobj = csel ? tconf : t[9];

            float dx = pxy0 - txy0, dy = pxy1 - txy1;
            float dw = pwh0 - sqrtf(twh0), dh = pwh1 - sqrtf(twh1);
            a_loc += m * (0.5f * (dx*dx + dy*dy) + 0.5f * (dw*dw + dh*dh));

            float dob = pobj - tobj;
            a_obj += m * dob * dob;

            float nm = (tconf == 0.0f) ? 1.0f : 0.0f;
            float d4 = p[4] - tconf, d9 = p[9] - t[9];
            a_no += nm * (d4 * d4 + d9 * d9);

            a_nob += m;
            a_nno += nm;

            int   tcls  = 0;
            float tbest = t[10];
            #pragma unroll
            for (int i = 1; i < CC; ++i) {
                float v = t[10 + i];
                if (v > tbest) { tbest = v; tcls = i; }
            }
            float mx = p[10];
            #pragma unroll
            for (int i = 1; i < CC; ++i) mx = fmaxf(mx, p[10 + i]);
            float e[CC];
            float Z = 0.f;
            #pragma unroll
            for (int i = 0; i < CC; ++i) { e[i] = __expf(p[10+i] - mx); Z += e[i]; }
            float rZ = 1.0f / Z;
            float Z2 = 0.f, sm_t = 0.f;
            #pragma unroll
            for (int i = 0; i < CC; ++i) {
                float sm = e[i] * rZ;          // in (0,1] -> exp safe
                Z2 += __expf(sm);
                if (i == tcls) sm_t = sm;
            }
            a_ce += m * (__logf(Z2) - sm_t);
        }
    }

    // wave(64) shuffle reduction of the 6 accumulators
    #pragma unroll
    for (int off = 32; off > 0; off >>= 1) {
        a_loc += __shfl_down(a_loc, off);
        a_ce  += __shfl_down(a_ce,  off);
        a_obj += __shfl_down(a_obj, off);
        a_no  += __shfl_down(a_no,  off);
        a_nob += __shfl_down(a_nob, off);
        a_nno += __shfl_down(a_nno, off);
    }

    __shared__ float red[4][6];
    int wave = tid >> 6;                 // 0 or 1
    int lane = tid & 63;
    if (tid < 6) { red[2][tid] = 0.f; red[3][tid] = 0.f; }  // rows 2,3 = 0
    if (lane == 0) {
        red[wave][0] = a_loc; red[wave][1] = a_ce;  red[wave][2] = a_obj;
        red[wave][3] = a_no;  red[wave][4] = a_nob; red[wave][5] = a_nno;
    }
    __syncthreads();
    if (tid < 6) {   // NO atomics: private row per block (same sum order as r7)
        float v = red[0][tid] + red[1][tid] + red[2][tid] + red[3][tid];
        ws[(size_t)blockIdx.x * ROW + tid] = v;
    }
}

__global__ __launch_bounds__(256) void yolo_reduce(
    const float* __restrict__ ws, float* __restrict__ out, int nb)
{
    float s[6] = {0.f, 0.f, 0.f, 0.f, 0.f, 0.f};
    for (int b = threadIdx.x; b < nb; b += 256) {
        #pragma unroll
        for (int j = 0; j < 6; ++j) s[j] += ws[(size_t)b * ROW + j];
    }
    #pragma unroll
    for (int off = 32; off > 0; off >>= 1) {
        #pragma unroll
        for (int j = 0; j < 6; ++j) s[j] += __shfl_down(s[j], off);
    }
    __shared__ float red[4][6];
    int wave = threadIdx.x >> 6;
    int lane = threadIdx.x & 63;
    if (lane == 0) {
        #pragma unroll
        for (int j = 0; j < 6; ++j) red[wave][j] = s[j];
    }
    __syncthreads();
    if (threadIdx.x == 0) {
        float t[6];
        #pragma unroll
        for (int j = 0; j < 6; ++j)
            t[j] = red[0][j] + red[1][j] + red[2][j] + red[3][j];
        out[0] = 5.0f * t[0];                     // loc_loss  (L_COORD = 5)
        out[1] = t[1] / fmaxf(t[4], 1.0f);        // cls_loss
        out[2] = t[2];                            // obj_loss
        out[3] = 0.5f * t[3] / fmaxf(t[5], 1.0f); // noobj_loss (L_NOOBJ = 0.5)
    }
}

extern "C" void kernel_launch(void* const* d_in, const int* in_sizes, int n_in,
                              void* d_out, int out_size, void* d_ws, size_t ws_size,
                              hipStream_t stream) {
    const float* pred   = (const float*)d_in[0];
    const float* target = (const float*)d_in[1];
    const int*   choice = (const int*)d_in[2];
    float* out = (float*)d_out;
    float* ws  = (float*)d_ws;

    int ncells  = in_sizes[2];                   // BATCH * S * S = 802816
    int nchunks = (ncells + CPB - 1) / CPB;      // 6272 exactly
    int grid    = GRID < nchunks ? GRID : nchunks;
    // ws usage: GRID * ROW * 4 B = 40 KB; rows [0,grid) all written before read
    yolo_main<<<grid, T, 0, stream>>>(pred, target, choice, ws, ncells, nchunks);
    yolo_reduce<<<1, 256, 0, stream>>>(ws, out, grid);
}

// Round 4
// 215.096 us; speedup vs baseline: 1.0070x; 1.0070x over previous
//
#include <hip/hip_runtime.h>
#include <math.h>

// YOLO loss: pred/target (BATCH,7,7,30) f32, choice (BATCH,7,7) i32
// -> 4 scalars (loc, cls, obj, noobj).
// Round-13: phase-free direct streaming + REGISTER double-buffer.
// r12 post-mortem: VGPR_Count=36 -> compiler serialized the 31 per-cell
// loads into ~6-outstanding batches -> 1.6 TB/s (Little's law match).
// Fix: (a) __launch_bounds__(T,2) raises VGPR cap to 256 so two full
// cell register sets fit; (b) explicit ping-pong prefetch: issue next
// cell's 31 loads before computing current; (c) sched_barrier(0) pins
// loads above compute. Compiler then emits counted vmcnt waits (the
// r11 lesson: counted waits good, barrier-phased lockstep bad).
// Lane->cell map, expression order, reduction tree identical to r7/r12
// baseline -> outputs bitwise identical.

constexpr int NCH = 30;    // 5*B + C
constexpr int CC  = 20;    // classes
constexpr int ROW = 8;     // floats per block's partial row (32 B)
constexpr int T   = 128;   // threads per block (2 waves) = cells per chunk
constexpr int CPB = 128;   // cells per chunk (== T)
constexpr int GRID = 1280; // same chunk->block mapping as baseline

struct CellRegs {
    float p[NCH];
    float t[NCH];
    int   c;
};

__device__ __forceinline__ void load_cell(
    const float* __restrict__ pred, const float* __restrict__ target,
    const int* __restrict__ choice, long long cell, long long ncells,
    CellRegs& R)
{
    long long cl = cell < ncells ? cell : ncells - 1;   // clamp (no tail: 802816 % 128 == 0)
    const float* sp  = pred   + cl * NCH;
    const float* stt = target + cl * NCH;
    #pragma unroll
    for (int i = 0; i < NCH / 2; ++i) {
        float2 v = *(const float2*)&sp[2 * i];
        R.p[2*i] = v.x; R.p[2*i+1] = v.y;
    }
    #pragma unroll
    for (int i = 0; i < NCH / 2; ++i) {
        float2 w = *(const float2*)&stt[2 * i];
        R.t[2*i] = w.x; R.t[2*i+1] = w.y;
    }
    R.c = choice[cl];
}

__device__ __forceinline__ void accum_cell(
    const CellRegs& R, float& a_loc, float& a_ce, float& a_obj,
    float& a_no, float& a_nob, float& a_nno)
{
    const float* p = R.p;
    const float* t = R.t;
    bool csel = R.c != 0;

    float tconf = t[4];
    bool  obj = tconf > 0.0f;
    float m = obj ? 1.0f : 0.0f;

    float pxy0 = csel ? p[0] : p[5];
    float pxy1 = csel ? p[1] : p[6];
    float pwh0 = csel ? p[2] : p[7];
    float pwh1 = csel ? p[3] : p[8];
    float pobj = csel ? p[4] : p[9];
    float txy0 = csel ? t[0] : t[5];
    float txy1 = csel ? t[1] : t[6];
    float twh0 = csel ? t[2] : t[7];
    float twh1 = csel ? t[3] : t[8];
    if (!obj) { twh0 = 1.0f; twh1 = 1.0f; }
    float tobj = csel ? tconf : t[9];

    float dx = pxy0 - txy0, dy = pxy1 - txy1;
    float dw = pwh0 - sqrtf(twh0), dh = pwh1 - sqrtf(twh1);
    a_loc += m * (0.5f * (dx*dx + dy*dy) + 0.5f * (dw*dw + dh*dh));

    float dob = pobj - tobj;
    a_obj += m * dob * dob;

    float nm = (tconf == 0.0f) ? 1.0f : 0.0f;
    float d4 = p[4] - tconf, d9 = p[9] - t[9];
    a_no += nm * (d4 * d4 + d9 * d9);

    a_nob += m;
    a_nno += nm;

    int   tcls  = 0;
    float tbest = t[10];
    #pragma unroll
    for (int i = 1; i < CC; ++i) {
        float v = t[10 + i];
        if (v > tbest) { tbest = v; tcls = i; }
    }
    float mx = p[10];
    #pragma unroll
    for (int i = 1; i < CC; ++i) mx = fmaxf(mx, p[10 + i]);
    float e[CC];
    float Z = 0.f;
    #pragma unroll
    for (int i = 0; i < CC; ++i) { e[i] = __expf(p[10+i] - mx); Z += e[i]; }
    float rZ = 1.0f / Z;
    float Z2 = 0.f, sm_t = 0.f;
    #pragma unroll
    for (int i = 0; i < CC; ++i) {
        float sm = e[i] * rZ;          // in (0,1] -> exp safe
        Z2 += __expf(sm);
        if (i == tcls) sm_t = sm;
    }
    a_ce += m * (__logf(Z2) - sm_t);
}

__global__ __launch_bounds__(T, 2) void yolo_main(
    const float* __restrict__ pred, const float* __restrict__ target,
    const int* __restrict__ choice, float* __restrict__ ws,
    int ncells, int nchunks)
{
    const int tid = threadIdx.x;

    float a_loc = 0.f, a_ce = 0.f, a_obj = 0.f, a_no = 0.f;
    float a_nob = 0.f, a_nno = 0.f;

    CellRegs A, B;
    long long c = blockIdx.x;
    bool any = c < nchunks;
    if (any) load_cell(pred, target, choice, c * CPB + tid, ncells, A);

    while (any) {
        long long c1 = c + GRID;
        bool h1 = c1 < nchunks;
        if (h1) load_cell(pred, target, choice, c1 * CPB + tid, ncells, B);
        __builtin_amdgcn_sched_barrier(0);     // loads stay above compute
        if (c * CPB + tid < (long long)ncells)
            accum_cell(A, a_loc, a_ce, a_obj, a_no, a_nob, a_nno);
        if (!h1) break;

        long long c2 = c1 + GRID;
        bool h2 = c2 < nchunks;
        if (h2) load_cell(pred, target, choice, c2 * CPB + tid, ncells, A);
        __builtin_amdgcn_sched_barrier(0);
        if (c1 * CPB + tid < (long long)ncells)
            accum_cell(B, a_loc, a_ce, a_obj, a_no, a_nob, a_nno);
        if (!h2) break;
        c = c2;
    }

    // wave(64) shuffle reduction of the 6 accumulators
    #pragma unroll
    for (int off = 32; off > 0; off >>= 1) {
        a_loc += __shfl_down(a_loc, off);
        a_ce  += __shfl_down(a_ce,  off);
        a_obj += __shfl_down(a_obj, off);
        a_no  += __shfl_down(a_no,  off);
        a_nob += __shfl_down(a_nob, off);
        a_nno += __shfl_down(a_nno, off);
    }

    __shared__ float red[4][6];
    int wave = tid >> 6;                 // 0 or 1
    int lane = tid & 63;
    if (tid < 6) { red[2][tid] = 0.f; red[3][tid] = 0.f; }  // rows 2,3 = 0
    if (lane == 0) {
        red[wave][0] = a_loc; red[wave][1] = a_ce;  red[wave][2] = a_obj;
        red[wave][3] = a_no;  red[wave][4] = a_nob; red[wave][5] = a_nno;
    }
    __syncthreads();
    if (tid < 6) {   // NO atomics: private row per block (same sum order as r7)
        float v = red[0][tid] + red[1][tid] + red[2][tid] + red[3][tid];
        ws[(size_t)blockIdx.x * ROW + tid] = v;
    }
}

__global__ __launch_bounds__(256) void yolo_reduce(
    const float* __restrict__ ws, float* __restrict__ out, int nb)
{
    float s[6] = {0.f, 0.f, 0.f, 0.f, 0.f, 0.f};
    for (int b = threadIdx.x; b < nb; b += 256) {
        #pragma unroll
        for (int j = 0; j < 6; ++j) s[j] += ws[(size_t)b * ROW + j];
    }
    #pragma unroll
    for (int off = 32; off > 0; off >>= 1) {
        #pragma unroll
        for (int j = 0; j < 6; ++j) s[j] += __shfl_down(s[j], off);
    }
    __shared__ float red[4][6];
    int wave = threadIdx.x >> 6;
    int lane = threadIdx.x & 63;
    if (lane == 0) {
        #pragma unroll
        for (int j = 0; j < 6; ++j) red[wave][j] = s[j];
    }
    __syncthreads();
    if (threadIdx.x == 0) {
        float t[6];
        #pragma unroll
        for (int j = 0; j < 6; ++j)
            t[j] = red[0][j] + red[1][j] + red[2][j] + red[3][j];
        out[0] = 5.0f * t[0];                     // loc_loss  (L_COORD = 5)
        out[1] = t[1] / fmaxf(t[4], 1.0f);        // cls_loss
        out[2] = t[2];                            // obj_loss
        out[3] = 0.5f * t[3] / fmaxf(t[5], 1.0f); // noobj_loss (L_NOOBJ = 0.5)
    }
}

extern "C" void kernel_launch(void* const* d_in, const int* in_sizes, int n_in,
                              void* d_out, int out_size, void* d_ws, size_t ws_size,
                              hipStream_t stream) {
    const float* pred   = (const float*)d_in[0];
    const float* target = (const float*)d_in[1];
    const int*   choice = (const int*)d_in[2];
    float* out = (float*)d_out;
    float* ws  = (float*)d_ws;

    int ncells  = in_sizes[2];                   // BATCH * S * S = 802816
    int nchunks = (ncells + CPB - 1) / CPB;      // 6272 exactly
    int grid    = GRID < nchunks ? GRID : nchunks;
    // ws usage: GRID * ROW * 4 B = 40 KB; rows [0,grid) all written before read
    yolo_main<<<grid, T, 0, stream>>>(pred, target, choice, ws, ncells, nchunks);
    yolo_reduce<<<1, 256, 0, stream>>>(ws, out, grid);
}

// Round 5
// 196.770 us; speedup vs baseline: 1.1008x; 1.0931x over previous
//
#include <hip/hip_runtime.h>
#include <math.h>

// YOLO loss: pred/target (BATCH,7,7,30) f32, choice (BATCH,7,7) i32
// -> 4 scalars (loc, cls, obj, noobj).
// Round-14: WAVE-PRIVATE staging — the untried cell of the design space.
// Evidence so far: coalesced staging (r7, 50us) beats direct gather
// (r12/r13, 80-84us: wave re-touches each line ~15x, ~2.4 TB/s cap);
// block-wide barriers tax r7 (4 waves drain vmcnt(0) together) and
// sank r11. Here: each 64-lane wave stages ITS OWN 64 cells via 15
// fully-coalesced nt dwordx4 loads/lane into registers (compiler emits
// exact counted vmcnt waits on reg deps), ds_writes its PRIVATE 15.9 KB
// LDS buffer, transposes via ds_read, computes. ZERO s_barrier in the
// loop; 31.7 KB LDS/block -> 5 blocks = 10 free-running wave-streams/CU
// (fill kernels prove free-running streams hit 6.8 TB/s).
// T=128, CPB=128, GRID=1280, cell = c*128+tid, same expression order,
// reduction tree, red rows 2,3 = 0 -> outputs bitwise identical to r7.

typedef float vf4 __attribute__((ext_vector_type(4)));

constexpr int NCH = 30;    // 5*B + C
constexpr int CC  = 20;    // classes
constexpr int ROW = 8;     // floats per block's partial row (32 B)
constexpr int T   = 128;   // threads per block (2 waves)
constexpr int CPB = 128;   // cells per chunk (2 waves x 64)
constexpr int GRID = 1280; // same chunk->block mapping as baseline

constexpr int WFLOATS = 64 * NCH * 2;        // 3840 floats staged per wave
constexpr int WSTRIDE = 3968;                // padded wave buffer (15872 B)

// Issue one wave's chunk: 15 nt dwordx4 (pred||target, fully coalesced)
// + 1 choice word per lane. Registers only — no LDS, no barriers.
__device__ __forceinline__ void stage_issue(
    const float* __restrict__ pred, const float* __restrict__ target,
    const int* __restrict__ choice, long long cc, long long ncells,
    int w, int l, vf4 (&st)[15], int& ci)
{
    long long cell0 = cc * CPB + w * 64;     // wave's first cell
    long long b30   = cell0 * NCH;           // float index of wave region
    long long lim   = ncells * (long long)NCH - 4;
    #pragma unroll
    for (int s = 0; s < 15; ++s) {
        int f = s * 256 + l * 4;             // float offset in 3840-float region
        long long g = b30 + (f < 1920 ? f : f - 1920);
        if (g > lim) g = lim;                // safety clamp (chunks are exact here)
        const float* src = (f < 1920) ? (pred + g) : (target + g);
        st[s] = __builtin_nontemporal_load((const vf4*)src);
    }
    long long ce = cell0 + l;
    ci = (ce < ncells) ? __builtin_nontemporal_load(&choice[ce]) : 0;
}

__global__ __launch_bounds__(T) void yolo_main(
    const float* __restrict__ pred, const float* __restrict__ target,
    const int* __restrict__ choice, float* __restrict__ ws,
    int ncells, int nchunks)
{
    __shared__ __align__(16) float sl[2 * WSTRIDE];   // 31744 B: 2 wave buffers
    const int tid = threadIdx.x;
    const int w = tid >> 6, l = tid & 63;
    float* wb = &sl[w * WSTRIDE];            // this wave's private buffer

    float a_loc = 0.f, a_ce = 0.f, a_obj = 0.f, a_no = 0.f;
    float a_nob = 0.f, a_nno = 0.f;

    vf4 st[15];
    int ci_n = 0;
    long long c = blockIdx.x;
    bool any = c < (long long)nchunks;
    if (any) stage_issue(pred, target, choice, c, ncells, w, l, st, ci_n);

    long long ccur = c;
    while (any) {
        // regs (chunk ccur) -> wave-private LDS; compiler inserts counted
        // vmcnt waits for st[] here (loads issued one full round earlier).
        #pragma unroll
        for (int s = 0; s < 15; ++s)
            *(vf4*)&wb[s * 256 + l * 4] = st[s];
        int myc = ci_n;

        long long cn = ccur + GRID;
        bool hn = cn < (long long)nchunks;
        if (hn) stage_issue(pred, target, choice, cn, ncells, w, l, st, ci_n);
        __builtin_amdgcn_sched_barrier(0);   // keep prefetch above compute

        long long cell = ccur * CPB + tid;
        if (cell < (long long)ncells) {
            const float* sp  = &wb[l * NCH];          // this lane's pred row
            const float* stt = &wb[1920 + l * NCH];   // this lane's target row
            float p[NCH], t[NCH];
            #pragma unroll
            for (int i = 0; i < NCH / 2; ++i) {
                float2 v = *(const float2*)&sp[2 * i];  p[2*i] = v.x; p[2*i+1] = v.y;
            }
            #pragma unroll
            for (int i = 0; i < NCH / 2; ++i) {
                float2 u = *(const float2*)&stt[2 * i]; t[2*i] = u.x; t[2*i+1] = u.y;
            }
            bool csel = myc != 0;

            float tconf = t[4];
            bool  obj = tconf > 0.0f;
            float m = obj ? 1.0f : 0.0f;

            float pxy0 = csel ? p[0] : p[5];
            float pxy1 = csel ? p[1] : p[6];
            float pwh0 = csel ? p[2] : p[7];
            float pwh1 = csel ? p[3] : p[8];
            float pobj = csel ? p[4] : p[9];
            float txy0 = csel ? t[0] : t[5];
            float txy1 = csel ? t[1] : t[6];
            float twh0 = csel ? t[2] : t[7];
            float twh1 = csel ? t[3] : t[8];
            if (!obj) { twh0 = 1.0f; twh1 = 1.0f; }
            float tobj = csel ? tconf : t[9];

            float dx = pxy0 - txy0, dy = pxy1 - txy1;
            float dw = pwh0 - sqrtf(twh0), dh = pwh1 - sqrtf(twh1);
            a_loc += m * (0.5f * (dx*dx + dy*dy) + 0.5f * (dw*dw + dh*dh));

            float dob = pobj - tobj;
            a_obj += m * dob * dob;

            float nm = (tconf == 0.0f) ? 1.0f : 0.0f;
            float d4 = p[4] - tconf, d9 = p[9] - t[9];
            a_no += nm * (d4 * d4 + d9 * d9);

            a_nob += m;
            a_nno += nm;

            int   tcls  = 0;
            float tbest = t[10];
            #pragma unroll
            for (int i = 1; i < CC; ++i) {
                float v = t[10 + i];
                if (v > tbest) { tbest = v; tcls = i; }
            }
            float mx = p[10];
            #pragma unroll
            for (int i = 1; i < CC; ++i) mx = fmaxf(mx, p[10 + i]);
            float e[CC];
            float Z = 0.f;
            #pragma unroll
            for (int i = 0; i < CC; ++i) { e[i] = __expf(p[10+i] - mx); Z += e[i]; }
            float rZ = 1.0f / Z;
            float Z2 = 0.f, sm_t = 0.f;
            #pragma unroll
            for (int i = 0; i < CC; ++i) {
                float sm = e[i] * rZ;          // in (0,1] -> exp safe
                Z2 += __expf(sm);
                if (i == tcls) sm_t = sm;
            }
            a_ce += m * (__logf(Z2) - sm_t);
        }

        if (!hn) break;
        ccur = cn;
    }

    // wave(64) shuffle reduction of the 6 accumulators
    #pragma unroll
    for (int off = 32; off > 0; off >>= 1) {
        a_loc += __shfl_down(a_loc, off);
        a_ce  += __shfl_down(a_ce,  off);
        a_obj += __shfl_down(a_obj, off);
        a_no  += __shfl_down(a_no,  off);
        a_nob += __shfl_down(a_nob, off);
        a_nno += __shfl_down(a_nno, off);
    }

    __shared__ float red[4][6];
    int lane = tid & 63;
    if (tid < 6) { red[2][tid] = 0.f; red[3][tid] = 0.f; }  // rows 2,3 = 0
    if (lane == 0) {
        red[w][0] = a_loc; red[w][1] = a_ce;  red[w][2] = a_obj;
        red[w][3] = a_no;  red[w][4] = a_nob; red[w][5] = a_nno;
    }
    __syncthreads();
    if (tid < 6) {   // NO atomics: private row per block (same sum order as r7)
        float v = red[0][tid] + red[1][tid] + red[2][tid] + red[3][tid];
        ws[(size_t)blockIdx.x * ROW + tid] = v;
    }
}

__global__ __launch_bounds__(256) void yolo_reduce(
    const float* __restrict__ ws, float* __restrict__ out, int nb)
{
    float s[6] = {0.f, 0.f, 0.f, 0.f, 0.f, 0.f};
    for (int b = threadIdx.x; b < nb; b += 256) {
        #pragma unroll
        for (int j = 0; j < 6; ++j) s[j] += ws[(size_t)b * ROW + j];
    }
    #pragma unroll
    for (int off = 32; off > 0; off >>= 1) {
        #pragma unroll
        for (int j = 0; j < 6; ++j) s[j] += __shfl_down(s[j], off);
    }
    __shared__ float red[4][6];
    int wave = threadIdx.x >> 6;
    int lane = threadIdx.x & 63;
    if (lane == 0) {
        #pragma unroll
        for (int j = 0; j < 6; ++j) red[wave][j] = s[j];
    }
    __syncthreads();
    if (threadIdx.x == 0) {
        float t[6];
        #pragma unroll
        for (int j = 0; j < 6; ++j)
            t[j] = red[0][j] + red[1][j] + red[2][j] + red[3][j];
        out[0] = 5.0f * t[0];                     // loc_loss  (L_COORD = 5)
        out[1] = t[1] / fmaxf(t[4], 1.0f);        // cls_loss
        out[2] = t[2];                            // obj_loss
        out[3] = 0.5f * t[3] / fmaxf(t[5], 1.0f); // noobj_loss (L_NOOBJ = 0.5)
    }
}

extern "C" void kernel_launch(void* const* d_in, const int* in_sizes, int n_in,
                              void* d_out, int out_size, void* d_ws, size_t ws_size,
                              hipStream_t stream) {
    const float* pred   = (const float*)d_in[0];
    const float* target = (const float*)d_in[1];
    const int*   choice = (const int*)d_in[2];
    float* out = (float*)d_out;
    float* ws  = (float*)d_ws;

    int ncells  = in_sizes[2];                   // BATCH * S * S = 802816
    int nchunks = (ncells + CPB - 1) / CPB;      // 6272 exactly
    int grid    = GRID < nchunks ? GRID : nchunks;
    // ws usage: GRID * ROW * 4 B = 40 KB; rows [0,grid) all written before read
    yolo_main<<<grid, T, 0, stream>>>(pred, target, choice, ws, ncells, nchunks);
    yolo_reduce<<<1, 256, 0, stream>>>(ws, out, grid);
}